// Round 9
// baseline (333.494 us; speedup 1.0000x reference)
//
#include <hip/hip_runtime.h>
#include <math.h>

#define NB 2
#define NL 1024
#define ND 768
#define NH 12
#define DH 64

typedef _Float16 f16;
typedef _Float16 f16x2 __attribute__((ext_vector_type(2)));
typedef _Float16 f16x4 __attribute__((ext_vector_type(4)));
typedef _Float16 f16x8 __attribute__((ext_vector_type(8)));
typedef float f32x4 __attribute__((ext_vector_type(4)));

#define MFMA16(a, b, c) __builtin_amdgcn_mfma_f32_16x16x32_f16((a), (b), (c), 0, 0, 0)

// XOR-swizzled f16 index into a pitch-64 row-major LDS tile (T2/G4).
#define SWZ(r, c) ((r) * 64 + ((c) ^ (((r) & 7) << 3)))

// LDS-only barrier (does not force vmcnt drain).
__device__ __forceinline__ void soft_barrier() {
    asm volatile("s_waitcnt lgkmcnt(0)\n\ts_barrier" ::: "memory");
}

// ---------------------------------------------------------------------------
// Kernel 0: prep (556 tiles).
//   tiles 0..431   : W{q,k,v} -> wt f16 [(mat*12+h)*64+n][k]   (transposed)
//   tiles 432..491 : ssan_w -> swt f16 [p][h][e][d]            (transposed)
//   tiles 492..555 : dist_emb fp32 -> de16 f16
// ---------------------------------------------------------------------------
__global__ __launch_bounds__(256) void prep_kernel(
    const float* __restrict__ Wq, const float* __restrict__ Wk,
    const float* __restrict__ Wv, const float* __restrict__ sw,
    const float* __restrict__ de,
    f16* __restrict__ wt, f16* __restrict__ swt, f16* __restrict__ de16)
{
    __shared__ float sT[64 * 66];
    const int t = threadIdx.x;
    const int tile = blockIdx.x;

    if (tile >= 492) {
        const int base = (tile - 492) * 2048 + t * 8;
        if (base < 2047 * 64) {
            float4 a = *(const float4*)&de[base];
            float4 b = *(const float4*)&de[base + 4];
            f16x8 hv;
            hv[0] = (f16)a.x; hv[1] = (f16)a.y; hv[2] = (f16)a.z; hv[3] = (f16)a.w;
            hv[4] = (f16)b.x; hv[5] = (f16)b.y; hv[6] = (f16)b.z; hv[7] = (f16)b.w;
            *(f16x8*)&de16[base] = hv;
        }
        return;
    }

    const float* S; f16* D; int sRS, dRS;
    if (tile < 432) {
        const int mat = tile / 144, r2 = tile % 144, ht = r2 / 12, kt = r2 % 12;
        const float* W = (mat == 0) ? Wq : (mat == 1) ? Wk : Wv;
        S = W + (size_t)(kt * 64) * ND + ht * 64;
        D = wt + (size_t)((mat * NH + ht) * 64) * ND + kt * 64;
        sRS = ND; dRS = ND;
    } else {
        const int i = tile - 432;
        S = sw + (size_t)i * 4096;
        D = swt + (size_t)i * 4096;
        sRS = 64; dRS = 64;
    }

    {
        const int kk = t >> 2, nb = (t & 3) * 16;
        float v[16];
        #pragma unroll
        for (int j = 0; j < 4; ++j)
            *(float4*)&v[4 * j] = *(const float4*)&S[(size_t)kk * sRS + nb + 4 * j];
        #pragma unroll
        for (int jj = 0; jj < 16; ++jj)
            sT[(nb + jj) * 66 + kk] = v[jj];
    }
    soft_barrier();
    {
        const int n = t >> 2, kb = (t & 3) * 16;
        f16 tmp[16];
        #pragma unroll
        for (int j = 0; j < 8; ++j) {
            float2 x = *(float2*)&sT[n * 66 + kb + 2 * j];
            tmp[2 * j]     = (f16)x.x;
            tmp[2 * j + 1] = (f16)x.y;
        }
        *(f16x8*)&D[(size_t)n * dRS + kb]     = *(f16x8*)&tmp[0];
        *(f16x8*)&D[(size_t)n * dRS + kb + 8] = *(f16x8*)&tmp[8];
    }
}

// ---------------------------------------------------------------------------
// Kernel A v3b: QKV GEMM 64(M) x 128(N), BK=64; grid 32x18 = 576 blocks.
// A-operand read directly from hs fp32 (in-register f16 conversion).
// One barrier per K-iter, double-buffered swizzled LDS.
// Epilogue via sC (V stored transposed).  (unchanged from round 7)
// ---------------------------------------------------------------------------
__global__ __launch_bounds__(256, 2) void qkv_kernel(
    const float* __restrict__ hs, const f16* __restrict__ wt,
    const float* __restrict__ bq, const float* __restrict__ bk,
    const float* __restrict__ bv,
    f16* __restrict__ qf, f16* __restrict__ kf, f16* __restrict__ vt)
{
    __shared__ f16 sA[2][64 * 64];      // 16,384 B
    __shared__ f16 sB2[2][128 * 64];    // 32,768 B; reused as sC in epilogue

    const int m0 = blockIdx.x * 64;
    const int n0 = blockIdx.y * 128;
    const int mat = n0 / 768;
    const int h0  = (n0 % 768) / 64;     // first of the 2 heads in this tile
    const int bb  = m0 >> 10;
    const int l0  = m0 & 1023;

    const int t = threadIdx.x, lane = t & 63, w = t >> 6;
    const int quad = lane >> 4, l15 = lane & 15;
    const int wm = w >> 1, wn = w & 1;

    const float* bias = (mat == 0) ? bq : (mat == 1) ? bk : bv;

    const int arow = t >> 2, acb = (t & 3) * 16;
    const int brow = t >> 1, bcb = (t & 1) * 32;
    const float* Ag = hs + (size_t)(m0 + arow) * ND + acb;
    const f16*   Bg = wt + (size_t)(n0 + brow) * ND + bcb;

    f16x8 ar[2], br[4];
    f32x4 acc[2][4];
    #pragma unroll
    for (int mi = 0; mi < 2; ++mi)
        #pragma unroll
        for (int ni = 0; ni < 4; ++ni)
            acc[mi][ni] = (f32x4){0.f, 0.f, 0.f, 0.f};

    auto loadA = [&](int k0) {
        float4 a0 = *(const float4*)&Ag[k0];
        float4 a1 = *(const float4*)&Ag[k0 + 4];
        float4 a2 = *(const float4*)&Ag[k0 + 8];
        float4 a3 = *(const float4*)&Ag[k0 + 12];
        f16x8 h0, h1;
        h0[0] = (f16)a0.x; h0[1] = (f16)a0.y; h0[2] = (f16)a0.z; h0[3] = (f16)a0.w;
        h0[4] = (f16)a1.x; h0[5] = (f16)a1.y; h0[6] = (f16)a1.z; h0[7] = (f16)a1.w;
        h1[0] = (f16)a2.x; h1[1] = (f16)a2.y; h1[2] = (f16)a2.z; h1[3] = (f16)a2.w;
        h1[4] = (f16)a3.x; h1[5] = (f16)a3.y; h1[6] = (f16)a3.z; h1[7] = (f16)a3.w;
        ar[0] = h0; ar[1] = h1;
    };

    // prologue: stage K-tile 0
    loadA(0);
    #pragma unroll
    for (int j = 0; j < 4; ++j) br[j] = *(const f16x8*)&Bg[8 * j];
    *(f16x8*)&sA[0][SWZ(arow, acb)]     = ar[0];
    *(f16x8*)&sA[0][SWZ(arow, acb + 8)] = ar[1];
    #pragma unroll
    for (int j = 0; j < 4; ++j)
        *(f16x8*)&sB2[0][SWZ(brow, bcb + 8 * j)] = br[j];

    for (int kt2 = 0; kt2 < 12; ++kt2) {
        const int cur = kt2 & 1;
        soft_barrier();                    // buf(cur) published
        if (kt2 < 11) {
            const int k0 = (kt2 + 1) * 64;
            loadA(k0);
            #pragma unroll
            for (int j = 0; j < 4; ++j) br[j] = *(const f16x8*)&Bg[k0 + 8 * j];
        }
        #pragma unroll
        for (int kk = 0; kk < 64; kk += 32) {
            const int ko = kk + quad * 8;
            f16x8 af[2], bf[4];
            #pragma unroll
            for (int mi = 0; mi < 2; ++mi)
                af[mi] = *(f16x8*)&sA[cur][SWZ(32 * wm + 16 * mi + l15, ko)];
            #pragma unroll
            for (int ni = 0; ni < 4; ++ni)
                bf[ni] = *(f16x8*)&sB2[cur][SWZ(64 * wn + 16 * ni + l15, ko)];
            #pragma unroll
            for (int mi = 0; mi < 2; ++mi)
                #pragma unroll
                for (int ni = 0; ni < 4; ++ni)
                    acc[mi][ni] = MFMA16(af[mi], bf[ni], acc[mi][ni]);
        }
        if (kt2 < 11) {
            *(f16x8*)&sA[cur ^ 1][SWZ(arow, acb)]     = ar[0];
            *(f16x8*)&sA[cur ^ 1][SWZ(arow, acb + 8)] = ar[1];
            #pragma unroll
            for (int j = 0; j < 4; ++j)
                *(f16x8*)&sB2[cur ^ 1][SWZ(brow, bcb + 8 * j)] = br[j];
        }
    }
    soft_barrier();                        // all MFMA reads done; reuse LDS

    // ---- epilogue via sC (in sB2): q/k [64][136]; V transposed [128][72] ----
    f16* sC = (f16*)sB2;
    float bz[4];
    #pragma unroll
    for (int ni = 0; ni < 4; ++ni)
        bz[ni] = bias[(n0 % 768) + 64 * wn + 16 * ni + l15];

    #pragma unroll
    for (int mi = 0; mi < 2; ++mi)
        #pragma unroll
        for (int ni = 0; ni < 4; ++ni) {
            const int col = 64 * wn + 16 * ni + l15;
            #pragma unroll
            for (int r = 0; r < 4; ++r) {
                const int row = 32 * wm + 16 * mi + 4 * quad + r;
                const f16 v = (f16)(acc[mi][ni][r] + bz[ni]);
                if (mat == 2) sC[col * 72 + row]  = v;     // transposed
                else          sC[row * 136 + col] = v;
            }
        }
    soft_barrier();

    if (mat < 2) {
        const int r = t >> 2, q = t & 3;
        const int col0 = 32 * q;
        f16* dst = ((mat == 0) ? qf : kf)
                 + ((size_t)(bb * NH + h0 + (q >> 1)) * NL + l0 + r) * DH + 32 * (q & 1);
        #pragma unroll
        for (int j = 0; j < 4; ++j)
            *(f16x8*)&dst[8 * j] = *(f16x8*)&sC[r * 136 + col0 + 8 * j];
    } else {
        const int c = t >> 1, half = t & 1;
        f16* dst = vt + ((size_t)(bb * NH + h0 + (c >> 6)) * DH + (c & 63)) * NL
                 + l0 + 32 * half;
        #pragma unroll
        for (int j = 0; j < 4; ++j)
            *(f16x8*)&dst[8 * j] = *(f16x8*)&sC[c * 72 + 32 * half + 8 * j];
    }
}

// ---------------------------------------------------------------------------
// Kernel C: f16-MFMA flash attention, fused positional band-GEMMs, fused qw.
// Round-16 = round-7 body (best measured: attn 104 us, zero spill) + two
// correctness-neutral micro-adds:
//   * T5 s_setprio(1) around the score-MFMA and PV-MFMA clusters.  Regime:
//     2 independent blocks/CU at unrelated kt phases -> cross-block wave
//     role diversity (m191 mechanism).
//   * Bijective XCD swizzle of the grid (768 = 8*96): linear id n ->
//     (n&7)*96 + (n>>3); each XCD owns 3 complete bh groups (32 l0-tiles
//     sharing the same 128 KB K/V) -> K/V XCD-L2-local.
// Occupancy postscript (rounds 6-8): OccupancyPercent pinned at ~17% for
// LDS 68K/54K/46K -> 2 blocks/CU is the operating point; LDS-diet lever
// falsified (effective schedulable pool ~128 KiB).  vfrag direct-V (round 8)
// spilled (+8 VGPR past the 128 cliff) and regressed; sVt staging restored.
// Phase schedule (3 barriers/kt, T14 issue-early/write-late):
//   B: band GEMMs                                     | bar_a
//   C: write V(kt); issue K/V/E(kt+1); score MFMAs    | bar_b
//   D: softmax; write K/E(kt+1); issue pf(kt+1)       | bar_c
//   E: PV MFMA (no barrier; loops to B)
// ---------------------------------------------------------------------------
__global__ __launch_bounds__(256, 2) void attn_kernel(
    const f16* __restrict__ qf, const f16* __restrict__ kf,
    const f16* __restrict__ vt, const f16* __restrict__ swt,
    const float* __restrict__ mask, const float* __restrict__ struct_m,
    const f16* __restrict__ de16, const float* __restrict__ abs_bias,
    float* __restrict__ out)
{
    __shared__ f16 sK[64 * 64];       //  8,192
    __shared__ f16 sVt[64 * 64];      //  8,192
    __shared__ f16 sE[96 * 64];       // 12,288 (rows 0..94 valid; qw scratch in prologue)
    __shared__ f16 sQEl[96 * 34];     //  6,528
    __shared__ f16 sKEl[96 * 34];     //  6,528
    __shared__ float sS[32 * 66];     //  8,448 (cols 0..63 scores; 64 alpha; 65 l)
    __shared__ f16 sP[32 * 64];       //  4,096            => total 54,272 B

    // Bijective XCD swizzle: linear id n in [0,768); dispatch round-robins
    // n%8 across XCDs, so n' = (n&7)*96 + (n>>3) gives each XCD a contiguous
    // 96-block range = 3 complete bh groups.
    const int nlin = blockIdx.x + 32 * blockIdx.y;
    const int nsw  = (nlin & 7) * 96 + (nlin >> 3);
    const int l0 = (nsw & 31) * 32;
    const int bh = nsw >> 5;
    const int bb = bh / NH, h = bh % NH;
    const int t  = threadIdx.x;
    const int lane  = t & 63;
    const int w     = t >> 6;       // 0..3
    const int quad  = lane >> 4;
    const int l15   = lane & 15;
    const int msub  = w >> 1;       // 0..1
    const int npair = w & 1;        // 0..1

    f16x8 aQ[2], aW[5][2];
    {
        const size_t qrow = ((size_t)bh * NL + l0 + 16 * msub + l15) * DH;
        #pragma unroll
        for (int K = 0; K < 2; ++K)
            aQ[K] = *(const f16x8*)&qf[qrow + 32 * K + 8 * quad];
    }

    // ---- Fused qw: aW[p] fragments of Q_tile @ ssan_w[p,h] (sE as scratch) ----
    {
        #pragma unroll
        for (int b = 0; b < 2; ++b) {
            const int pb0  = (b == 0) ? 0 : 3;
            const int pcnt = (b == 0) ? 3 : 2;
            #pragma unroll
            for (int pi = 0; pi < 3; ++pi) {
                if (pi < pcnt) {
                    const int p = pb0 + pi;
                    const f16* Wp = swt + ((size_t)(p * NH + h)) * 64 * 64;
                    #pragma unroll
                    for (int ntl = 0; ntl < 2; ++ntl) {
                        const int nt = 2 * npair + ntl;
                        f32x4 c = (f32x4){0.f, 0.f, 0.f, 0.f};
                        #pragma unroll
                        for (int K = 0; K < 2; ++K) {
                            f16x8 bw = *(const f16x8*)&Wp[(size_t)(16 * nt + l15) * 64 + 32 * K + 8 * quad];
                            c = MFMA16(aQ[K], bw, c);
                        }
                        #pragma unroll
                        for (int r = 0; r < 4; ++r)
                            sE[SWZ(pi * 32 + 16 * msub + 4 * quad + r, 16 * nt + l15)] = (f16)c[r];
                    }
                }
            }
            soft_barrier();
            #pragma unroll
            for (int pi = 0; pi < 3; ++pi) {
                if (pi < pcnt) {
                    #pragma unroll
                    for (int K = 0; K < 2; ++K)
                        aW[pb0 + pi][K] =
                            *(const f16x8*)&sE[SWZ(pi * 32 + 16 * msub + l15, 32 * K + 8 * quad)];
                }
            }
            soft_barrier();
        }
    }

    float ab[5];
    #pragma unroll
    for (int p = 0; p < 5; ++p) ab[p] = abs_bias[p * NH + h];

    float pf_st[5][2][4], pf_mask[2];
    f16x8 kreg[2], vreg[2], ereg[3];     // single-buffer staging registers

    const int krow = t >> 3, kcol = (t & 7) * 8;   // shared staging mapping

    auto issue_k = [&](int r0s) {
        const f16* ks = kf + ((size_t)bh * NL + r0s) * DH;
        kreg[0] = *(const f16x8*)&ks[krow * 64 + kcol];
        kreg[1] = *(const f16x8*)&ks[(krow + 32) * 64 + kcol];
    };
    auto write_k = [&]() {
        *(f16x8*)&sK[SWZ(krow, kcol)]      = kreg[0];
        *(f16x8*)&sK[SWZ(krow + 32, kcol)] = kreg[1];
    };
    auto issue_v = [&](int r0s) {
        const f16* vs = vt + (size_t)bh * DH * NL + r0s;
        vreg[0] = *(const f16x8*)&vs[(size_t)krow * NL + kcol];
        vreg[1] = *(const f16x8*)&vs[(size_t)(krow + 32) * NL + kcol];
    };
    auto write_v = [&]() {
        *(f16x8*)&sVt[SWZ(krow, kcol)]      = vreg[0];
        *(f16x8*)&sVt[SWZ(krow + 32, kcol)] = vreg[1];
    };
    auto issue_E = [&](int r0s) {
        const int ebase = l0 - r0s + 960;
        #pragma unroll
        for (int p2 = 0; p2 < 3; ++p2) {
            const int idx = t + 256 * p2;
            const int er = idx >> 3, colE = (idx & 7) * 8;
            if (er < 95)
                ereg[p2] = *(const f16x8*)&de16[(size_t)(ebase + er) * DH + colE];
        }
    };
    auto write_E = [&]() {
        #pragma unroll
        for (int p2 = 0; p2 < 3; ++p2) {
            const int idx = t + 256 * p2;
            const int er = idx >> 3, colE = (idx & 7) * 8;
            if (er < 95)
                *(f16x8*)&sE[SWZ(er, colE)] = ereg[p2];
        }
    };
    auto prefetch = [&](int r0s) {
        #pragma unroll
        for (int n = 0; n < 2; ++n) {
            const int j = 32 * npair + 16 * n + l15;
            pf_mask[n] = mask[bb * NL + r0s + j];
            #pragma unroll
            for (int r = 0; r < 4; ++r) {
                const int i = 16 * msub + 4 * quad + r;
                #pragma unroll
                for (int p = 0; p < 5; ++p)
                    pf_st[p][n][r] =
                        struct_m[((size_t)(p * NB + bb) * NL + l0 + i) * NL + r0s + j];
            }
        }
    };

    // prologue: stage K(0)/E(0) directly; V(0) stays in vreg (written in C(0))
    issue_k(0);
    issue_E(0);
    issue_v(0);
    prefetch(0);
    write_k();
    write_E();

    const int sm_i = t >> 3;
    const int sm_jb = t & 7;
    float m_cur = -INFINITY, l_cur = 0.f;
    f32x4 O[2];
    O[0] = (f32x4){0.f, 0.f, 0.f, 0.f};
    O[1] = (f32x4){0.f, 0.f, 0.f, 0.f};

    soft_barrier();                        // kt=0 staging visible

    for (int kt = 0; kt < 16; ++kt) {

        // ---- Phase B: positional band GEMMs (slim per-wave assignment) ----
        {
            // KE: jt = w, nt = 3-w+c (c = 0..2)
            f16x8 ak0 = *(f16x8*)&sK[SWZ(16 * w + l15, quad * 8)];
            f16x8 ak1 = *(f16x8*)&sK[SWZ(16 * w + l15, 32 + quad * 8)];
            #pragma unroll
            for (int c = 0; c < 3; ++c) {
                const int nt = 3 - w + c;
                f16x8 e0 = *(f16x8*)&sE[SWZ(16 * nt + l15, quad * 8)];
                f16x8 e1 = *(f16x8*)&sE[SWZ(16 * nt + l15, 32 + quad * 8)];
                f32x4 ck = (f32x4){0.f, 0.f, 0.f, 0.f};
                ck = MFMA16(ak0, e0, ck);
                ck = MFMA16(ak1, e1, ck);
                const int base = (16 * nt + l15) * 34 + 16 * w + 4 * quad;
                f16x2 lo = {(f16)ck[0], (f16)ck[1]};
                f16x2 hi = {(f16)ck[2], (f16)ck[3]};
                *(f16x2*)&sKEl[base]     = lo;
                *(f16x2*)&sKEl[base + 2] = hi;
            }
            // QE: mi = msub, nt = qs..qs+qc-1  (A-frag = resident aQ)
            const int qs = 3 * npair + msub;
            const int qc = 3 - npair;
            #pragma unroll
            for (int c = 0; c < 3; ++c) {
                if (c < qc) {
                    const int nt = qs + c;
                    f16x8 e0 = *(f16x8*)&sE[SWZ(16 * nt + l15, quad * 8)];
                    f16x8 e1 = *(f16x8*)&sE[SWZ(16 * nt + l15, 32 + quad * 8)];
                    f32x4 cq = (f32x4){0.f, 0.f, 0.f, 0.f};
                    cq = MFMA16(aQ[0], e0, cq);
                    cq = MFMA16(aQ[1], e1, cq);
                    const int base = (16 * nt + l15) * 34 + 16 * msub + 4 * quad;
                    f16x2 lo = {(f16)cq[0], (f16)cq[1]};
                    f16x2 hi = {(f16)cq[2], (f16)cq[3]};
                    *(f16x2*)&sQEl[base]     = lo;
                    *(f16x2*)&sQEl[base + 2] = hi;
                }
            }
        }
        soft_barrier();                    // bar_a: sQEl/sKEl published

        // ---- Phase C: write V(kt); issue K/V/E(kt+1); score MFMAs ----
        {
            write_v();                     // ds_write reads vreg (WAR-safe before reissue)
            if (kt < 15) {
                issue_k((kt + 1) * 64);
                issue_v((kt + 1) * 64);
                issue_E((kt + 1) * 64);
            }

            f32x4 acc[2][6];
            #pragma unroll
            for (int n = 0; n < 2; ++n)
                #pragma unroll
                for (int p = 0; p < 6; ++p)
                    acc[n][p] = (f32x4){0.f, 0.f, 0.f, 0.f};

            __builtin_amdgcn_s_setprio(1);
            #pragma unroll
            for (int K = 0; K < 2; ++K) {
                const int koff = K * 32 + quad * 8;
                f16x8 bk2[2];
                #pragma unroll
                for (int n = 0; n < 2; ++n)
                    bk2[n] = *(f16x8*)&sK[SWZ(32 * npair + 16 * n + l15, koff)];
                #pragma unroll
                for (int n = 0; n < 2; ++n)
                    acc[n][0] = MFMA16(aQ[K], bk2[n], acc[n][0]);
                #pragma unroll
                for (int p = 0; p < 5; ++p)
                    #pragma unroll
                    for (int n = 0; n < 2; ++n)
                        acc[n][1 + p] = MFMA16(aW[p][K], bk2[n], acc[n][1 + p]);
            }
            __builtin_amdgcn_s_setprio(0);

            #pragma unroll
            for (int n = 0; n < 2; ++n) {
                const int j = 32 * npair + 16 * n + l15;
                #pragma unroll
                for (int r = 0; r < 4; ++r) {
                    const int i = 16 * msub + 4 * quad + r;
                    const int tp = i - j + 63;
                    float posv = (float)sQEl[tp * 34 + i] + (float)sKEl[tp * 34 + j];
                    float s = (acc[n][0][r] + posv) * 0.125f + pf_mask[n];
                    #pragma unroll
                    for (int p = 0; p < 5; ++p)
                        s += (acc[n][1 + p][r] + ab[p]) * pf_st[p][n][r];
                    sS[i * 66 + j] = s;
                }
            }
        }
        soft_barrier();                    // bar_b: sS published

        // ---- Phase D: softmax; write K/E(kt+1); issue pf(kt+1) ----
        {
            float sv[8];
            float smax = -INFINITY;
            #pragma unroll
            for (int k = 0; k < 8; ++k) {
                sv[k] = sS[sm_i * 66 + sm_jb + 8 * k];
                smax = fmaxf(smax, sv[k]);
            }
            #pragma unroll
            for (int off = 4; off > 0; off >>= 1)
                smax = fmaxf(smax, __shfl_xor(smax, off, 8));
            const float m_new = fmaxf(m_cur, smax);
            const float alpha = __expf(m_cur - m_new);
            float rsum = 0.f;
            #pragma unroll
            for (int k = 0; k < 8; ++k) {
                float p = __expf(sv[k] - m_new);
                sP[SWZ(sm_i, sm_jb + 8 * k)] = (f16)p;
                rsum += p;
            }
            #pragma unroll
            for (int off = 4; off > 0; off >>= 1)
                rsum += __shfl_xor(rsum, off, 8);
            l_cur = l_cur * alpha + rsum;
            m_cur = m_new;
            if (sm_jb == 0) {
                sS[sm_i * 66 + 64] = alpha;
                sS[sm_i * 66 + 65] = l_cur;
            }

            if (kt < 15) {
                write_k();                 // vmcnt covered by C compute + softmax
                write_E();
                prefetch((kt + 1) * 64);   // reg-dest loads for next C epilogue
            }
        }
        soft_barrier();                    // bar_c: sP/alpha + staging published

        // ---- Phase E: PV MFMA only ----
        {
            float a4[4];
            #pragma unroll
            for (int r = 0; r < 4; ++r)
                a4[r] = sS[(16 * msub + 4 * quad + r) * 66 + 64];
            #pragma unroll
            for (int n = 0; n < 2; ++n)
                #pragma unroll
                for (int r = 0; r < 4; ++r) O[n][r] *= a4[r];

            __builtin_amdgcn_s_setprio(1);
            #pragma unroll
            for (int K = 0; K < 2; ++K) {
                const int koff = K * 32 + quad * 8;
                f16x8 pfr = *(f16x8*)&sP[SWZ(16 * msub + l15, koff)];
                #pragma unroll
                for (int n = 0; n < 2; ++n) {
                    f16x8 vfr = *(f16x8*)&sVt[SWZ(32 * npair + 16 * n + l15, koff)];
                    O[n] = MFMA16(pfr, vfr, O[n]);
                }
            }
            __builtin_amdgcn_s_setprio(0);
        }
    }

    float linv[4];
    #pragma unroll
    for (int r = 0; r < 4; ++r)
        linv[r] = 1.0f / sS[(16 * msub + 4 * quad + r) * 66 + 65];
    #pragma unroll
    for (int n = 0; n < 2; ++n) {
        const int dh = 32 * npair + 16 * n + l15;
        #pragma unroll
        for (int r = 0; r < 4; ++r) {
            const int i = 16 * msub + 4 * quad + r;
            out[((size_t)bb * NL + l0 + i) * ND + h * DH + dh] = O[n][r] * linv[r];
        }
    }
}

// ---------------------------------------------------------------------------
extern "C" void kernel_launch(void* const* d_in, const int* in_sizes, int n_in,
                              void* d_out, int out_size, void* d_ws, size_t ws_size,
                              hipStream_t stream) {
    const float* hs   = (const float*)d_in[0];
    const float* mask = (const float*)d_in[1];
    const float* stm  = (const float*)d_in[2];
    const float* Wq   = (const float*)d_in[3];
    const float* bq   = (const float*)d_in[4];
    const float* Wk   = (const float*)d_in[5];
    const float* bk   = (const float*)d_in[6];
    const float* Wv   = (const float*)d_in[7];
    const float* bv   = (const float*)d_in[8];
    const float* de   = (const float*)d_in[9];
    const float* sw   = (const float*)d_in[10];
    const float* abb  = (const float*)d_in[11];
    float* outp = (float*)d_out;

    const size_t NQKV = (size_t)NB * NH * NL * DH;       // 1,572,864
    char* ws = (char*)d_ws;
    f16* qf   = (f16*)ws;                 ws += NQKV * 2;
    f16* kf   = (f16*)ws;                 ws += NQKV * 2;
    f16* vtb  = (f16*)ws;                 ws += NQKV * 2;
    f16* wt   = (f16*)ws;                 ws += (size_t)2304 * 768 * 2;
    f16* swt  = (f16*)ws;                 ws += (size_t)245760 * 2;
    f16* de16 = (f16*)ws;                 // 2047*64 f16 = 262 KB

    prep_kernel<<<556, 256, 0, stream>>>(Wq, Wk, Wv, sw, de, wt, swt, de16);
    qkv_kernel<<<dim3(32, 18), 256, 0, stream>>>(hs, wt, bq, bk, bv, qf, kf, vtb);
    attn_kernel<<<dim3(32, 24), 256, 0, stream>>>(qf, kf, vtb, swt,
                                                  mask, stm, de16, abb, outp);
}

// Round 10
// 215.412 us; speedup vs baseline: 1.5482x; 1.5482x over previous
//
#include <hip/hip_runtime.h>
#include <math.h>

#define NB 2
#define NL 1024
#define ND 768
#define NH 12
#define DH 64

typedef _Float16 f16;
typedef _Float16 f16x2 __attribute__((ext_vector_type(2)));
typedef _Float16 f16x4 __attribute__((ext_vector_type(4)));
typedef _Float16 f16x8 __attribute__((ext_vector_type(8)));
typedef float f32x4 __attribute__((ext_vector_type(4)));

#define MFMA16(a, b, c) __builtin_amdgcn_mfma_f32_16x16x32_f16((a), (b), (c), 0, 0, 0)

// XOR-swizzled f16 index into a pitch-64 row-major LDS tile (T2/G4).
#define SWZ(r, c) ((r) * 64 + ((c) ^ (((r) & 7) << 3)))

// LDS-only barrier (does not force vmcnt drain).
__device__ __forceinline__ void soft_barrier() {
    asm volatile("s_waitcnt lgkmcnt(0)\n\ts_barrier" ::: "memory");
}

// ---------------------------------------------------------------------------
// Kernel 0: prep (556 tiles; hs->f16 folded into qkv).
//   tiles 0..431   : W{q,k,v} -> wt f16 [(mat*12+h)*64+n][k]   (transposed)
//   tiles 432..491 : ssan_w -> swt f16 [p][h][e][d]            (transposed)
//   tiles 492..555 : dist_emb fp32 -> de16 f16
// ---------------------------------------------------------------------------
__global__ __launch_bounds__(256) void prep_kernel(
    const float* __restrict__ Wq, const float* __restrict__ Wk,
    const float* __restrict__ Wv, const float* __restrict__ sw,
    const float* __restrict__ de,
    f16* __restrict__ wt, f16* __restrict__ swt, f16* __restrict__ de16)
{
    __shared__ float sT[64 * 66];
    const int t = threadIdx.x;
    const int tile = blockIdx.x;

    if (tile >= 492) {
        const int base = (tile - 492) * 2048 + t * 8;
        if (base < 2047 * 64) {
            float4 a = *(const float4*)&de[base];
            float4 b = *(const float4*)&de[base + 4];
            f16x8 hv;
            hv[0] = (f16)a.x; hv[1] = (f16)a.y; hv[2] = (f16)a.z; hv[3] = (f16)a.w;
            hv[4] = (f16)b.x; hv[5] = (f16)b.y; hv[6] = (f16)b.z; hv[7] = (f16)b.w;
            *(f16x8*)&de16[base] = hv;
        }
        return;
    }

    const float* S; f16* D; int sRS, dRS;
    if (tile < 432) {
        const int mat = tile / 144, r2 = tile % 144, ht = r2 / 12, kt = r2 % 12;
        const float* W = (mat == 0) ? Wq : (mat == 1) ? Wk : Wv;
        S = W + (size_t)(kt * 64) * ND + ht * 64;
        D = wt + (size_t)((mat * NH + ht) * 64) * ND + kt * 64;
        sRS = ND; dRS = ND;
    } else {
        const int i = tile - 432;
        S = sw + (size_t)i * 4096;
        D = swt + (size_t)i * 4096;
        sRS = 64; dRS = 64;
    }

    {
        const int kk = t >> 2, nb = (t & 3) * 16;
        float v[16];
        #pragma unroll
        for (int j = 0; j < 4; ++j)
            *(float4*)&v[4 * j] = *(const float4*)&S[(size_t)kk * sRS + nb + 4 * j];
        #pragma unroll
        for (int jj = 0; jj < 16; ++jj)
            sT[(nb + jj) * 66 + kk] = v[jj];
    }
    soft_barrier();
    {
        const int n = t >> 2, kb = (t & 3) * 16;
        f16 tmp[16];
        #pragma unroll
        for (int j = 0; j < 8; ++j) {
            float2 x = *(float2*)&sT[n * 66 + kb + 2 * j];
            tmp[2 * j]     = (f16)x.x;
            tmp[2 * j + 1] = (f16)x.y;
        }
        *(f16x8*)&D[(size_t)n * dRS + kb]     = *(f16x8*)&tmp[0];
        *(f16x8*)&D[(size_t)n * dRS + kb + 8] = *(f16x8*)&tmp[8];
    }
}

// ---------------------------------------------------------------------------
// Kernel A v3b: QKV GEMM 64(M) x 128(N), BK=64; grid 32x18 = 576 blocks.
// A-operand read directly from hs fp32 (in-register f16 conversion).
// One barrier per K-iter, double-buffered swizzled LDS.
// Epilogue via sC (V stored transposed).
// ---------------------------------------------------------------------------
__global__ __launch_bounds__(256, 2) void qkv_kernel(
    const float* __restrict__ hs, const f16* __restrict__ wt,
    const float* __restrict__ bq, const float* __restrict__ bk,
    const float* __restrict__ bv,
    f16* __restrict__ qf, f16* __restrict__ kf, f16* __restrict__ vt)
{
    __shared__ f16 sA[2][64 * 64];      // 16,384 B
    __shared__ f16 sB2[2][128 * 64];    // 32,768 B; reused as sC in epilogue

    const int m0 = blockIdx.x * 64;
    const int n0 = blockIdx.y * 128;
    const int mat = n0 / 768;
    const int h0  = (n0 % 768) / 64;     // first of the 2 heads in this tile
    const int bb  = m0 >> 10;
    const int l0  = m0 & 1023;

    const int t = threadIdx.x, lane = t & 63, w = t >> 6;
    const int quad = lane >> 4, l15 = lane & 15;
    const int wm = w >> 1, wn = w & 1;

    const float* bias = (mat == 0) ? bq : (mat == 1) ? bk : bv;

    const int arow = t >> 2, acb = (t & 3) * 16;
    const int brow = t >> 1, bcb = (t & 1) * 32;
    const float* Ag = hs + (size_t)(m0 + arow) * ND + acb;
    const f16*   Bg = wt + (size_t)(n0 + brow) * ND + bcb;

    f16x8 ar[2], br[4];
    f32x4 acc[2][4];
    #pragma unroll
    for (int mi = 0; mi < 2; ++mi)
        #pragma unroll
        for (int ni = 0; ni < 4; ++ni)
            acc[mi][ni] = (f32x4){0.f, 0.f, 0.f, 0.f};

    auto loadA = [&](int k0) {
        float4 a0 = *(const float4*)&Ag[k0];
        float4 a1 = *(const float4*)&Ag[k0 + 4];
        float4 a2 = *(const float4*)&Ag[k0 + 8];
        float4 a3 = *(const float4*)&Ag[k0 + 12];
        f16x8 h0, h1;
        h0[0] = (f16)a0.x; h0[1] = (f16)a0.y; h0[2] = (f16)a0.z; h0[3] = (f16)a0.w;
        h0[4] = (f16)a1.x; h0[5] = (f16)a1.y; h0[6] = (f16)a1.z; h0[7] = (f16)a1.w;
        h1[0] = (f16)a2.x; h1[1] = (f16)a2.y; h1[2] = (f16)a2.z; h1[3] = (f16)a2.w;
        h1[4] = (f16)a3.x; h1[5] = (f16)a3.y; h1[6] = (f16)a3.z; h1[7] = (f16)a3.w;
        ar[0] = h0; ar[1] = h1;
    };

    // prologue: stage K-tile 0
    loadA(0);
    #pragma unroll
    for (int j = 0; j < 4; ++j) br[j] = *(const f16x8*)&Bg[8 * j];
    *(f16x8*)&sA[0][SWZ(arow, acb)]     = ar[0];
    *(f16x8*)&sA[0][SWZ(arow, acb + 8)] = ar[1];
    #pragma unroll
    for (int j = 0; j < 4; ++j)
        *(f16x8*)&sB2[0][SWZ(brow, bcb + 8 * j)] = br[j];

    for (int kt2 = 0; kt2 < 12; ++kt2) {
        const int cur = kt2 & 1;
        soft_barrier();                    // buf(cur) published
        if (kt2 < 11) {
            const int k0 = (kt2 + 1) * 64;
            loadA(k0);
            #pragma unroll
            for (int j = 0; j < 4; ++j) br[j] = *(const f16x8*)&Bg[k0 + 8 * j];
        }
        #pragma unroll
        for (int kk = 0; kk < 64; kk += 32) {
            const int ko = kk + quad * 8;
            f16x8 af[2], bf[4];
            #pragma unroll
            for (int mi = 0; mi < 2; ++mi)
                af[mi] = *(f16x8*)&sA[cur][SWZ(32 * wm + 16 * mi + l15, ko)];
            #pragma unroll
            for (int ni = 0; ni < 4; ++ni)
                bf[ni] = *(f16x8*)&sB2[cur][SWZ(64 * wn + 16 * ni + l15, ko)];
            #pragma unroll
            for (int mi = 0; mi < 2; ++mi)
                #pragma unroll
                for (int ni = 0; ni < 4; ++ni)
                    acc[mi][ni] = MFMA16(af[mi], bf[ni], acc[mi][ni]);
        }
        if (kt2 < 11) {
            *(f16x8*)&sA[cur ^ 1][SWZ(arow, acb)]     = ar[0];
            *(f16x8*)&sA[cur ^ 1][SWZ(arow, acb + 8)] = ar[1];
            #pragma unroll
            for (int j = 0; j < 4; ++j)
                *(f16x8*)&sB2[cur ^ 1][SWZ(brow, bcb + 8 * j)] = br[j];
        }
    }
    soft_barrier();                        // all MFMA reads done; reuse LDS

    // ---- epilogue via sC (in sB2): q/k [64][136]; V transposed [128][72] ----
    f16* sC = (f16*)sB2;
    float bz[4];
    #pragma unroll
    for (int ni = 0; ni < 4; ++ni)
        bz[ni] = bias[(n0 % 768) + 64 * wn + 16 * ni + l15];

    #pragma unroll
    for (int mi = 0; mi < 2; ++mi)
        #pragma unroll
        for (int ni = 0; ni < 4; ++ni) {
            const int col = 64 * wn + 16 * ni + l15;
            #pragma unroll
            for (int r = 0; r < 4; ++r) {
                const int row = 32 * wm + 16 * mi + 4 * quad + r;
                const f16 v = (f16)(acc[mi][ni][r] + bz[ni]);
                if (mat == 2) sC[col * 72 + row]  = v;     // transposed
                else          sC[row * 136 + col] = v;
            }
        }
    soft_barrier();

    if (mat < 2) {
        const int r = t >> 2, q = t & 3;
        const int col0 = 32 * q;
        f16* dst = ((mat == 0) ? qf : kf)
                 + ((size_t)(bb * NH + h0 + (q >> 1)) * NL + l0 + r) * DH + 32 * (q & 1);
        #pragma unroll
        for (int j = 0; j < 4; ++j)
            *(f16x8*)&dst[8 * j] = *(f16x8*)&sC[r * 136 + col0 + 8 * j];
    } else {
        const int c = t >> 1, half = t & 1;
        f16* dst = vt + ((size_t)(bb * NH + h0 + (c >> 6)) * DH + (c & 63)) * NL
                 + l0 + 32 * half;
        #pragma unroll
        for (int j = 0; j < 4; ++j)
            *(f16x8*)&dst[8 * j] = *(f16x8*)&sC[c * 72 + 32 * half + 8 * j];
    }
}

// ---------------------------------------------------------------------------
// Kernel C: f16-MFMA flash attention, fused positional band-GEMMs, fused qw.
// FINAL (revert to round-7-verified config: attn 104 us, zero spill).
// Session findings encoded here:
//   * 2 blocks/CU is the operating point: OccupancyPercent pinned ~17% for
//     LDS 68K/54K/46K (rounds 6-8) -> LDS-diet occupancy lever falsified.
//   * 128 VGPR is a hard cliff: +8..16 live VGPRs (V ping-pong r6, vfrag r8)
//     -> allocator spills to scratch (+17..130 MB WRITE), 1.3-2x regression.
//   * setprio + XCD-swizzle (r9): FETCH x3 (L2 locality destroyed; dispatch->
//     XCD mapping assumption wrong) + spills; absmax shifted -> reverted.
//   * In-register softmax (r1-r2) slower than sS round-trip at this width.
// Phase schedule (3 barriers/kt, T14 issue-early/write-late):
//   B: band GEMMs                                     | bar_a
//   C: write V(kt); issue K/V/E(kt+1); score MFMAs    | bar_b
//   D: softmax; write K/E(kt+1); issue pf(kt+1)       | bar_c
//   E: PV MFMA (no barrier; loops to B)
// ---------------------------------------------------------------------------
__global__ __launch_bounds__(256, 2) void attn_kernel(
    const f16* __restrict__ qf, const f16* __restrict__ kf,
    const f16* __restrict__ vt, const f16* __restrict__ swt,
    const float* __restrict__ mask, const float* __restrict__ struct_m,
    const f16* __restrict__ de16, const float* __restrict__ abs_bias,
    float* __restrict__ out)
{
    __shared__ f16 sK[64 * 64];       //  8,192
    __shared__ f16 sVt[64 * 64];      //  8,192
    __shared__ f16 sE[96 * 64];       // 12,288 (rows 0..94 valid; qw scratch in prologue)
    __shared__ f16 sQEl[96 * 34];     //  6,528
    __shared__ f16 sKEl[96 * 34];     //  6,528
    __shared__ float sS[32 * 66];     //  8,448 (cols 0..63 scores; 64 alpha; 65 l)
    __shared__ f16 sP[32 * 64];       //  4,096            => total 54,272 B

    const int l0 = blockIdx.x * 32;
    const int bh = blockIdx.y;
    const int bb = bh / NH, h = bh % NH;
    const int t  = threadIdx.x;
    const int lane  = t & 63;
    const int w     = t >> 6;       // 0..3
    const int quad  = lane >> 4;
    const int l15   = lane & 15;
    const int msub  = w >> 1;       // 0..1
    const int npair = w & 1;        // 0..1

    f16x8 aQ[2], aW[5][2];
    {
        const size_t qrow = ((size_t)bh * NL + l0 + 16 * msub + l15) * DH;
        #pragma unroll
        for (int K = 0; K < 2; ++K)
            aQ[K] = *(const f16x8*)&qf[qrow + 32 * K + 8 * quad];
    }

    // ---- Fused qw: aW[p] fragments of Q_tile @ ssan_w[p,h] (sE as scratch) ----
    {
        #pragma unroll
        for (int b = 0; b < 2; ++b) {
            const int pb0  = (b == 0) ? 0 : 3;
            const int pcnt = (b == 0) ? 3 : 2;
            #pragma unroll
            for (int pi = 0; pi < 3; ++pi) {
                if (pi < pcnt) {
                    const int p = pb0 + pi;
                    const f16* Wp = swt + ((size_t)(p * NH + h)) * 64 * 64;
                    #pragma unroll
                    for (int ntl = 0; ntl < 2; ++ntl) {
                        const int nt = 2 * npair + ntl;
                        f32x4 c = (f32x4){0.f, 0.f, 0.f, 0.f};
                        #pragma unroll
                        for (int K = 0; K < 2; ++K) {
                            f16x8 bw = *(const f16x8*)&Wp[(size_t)(16 * nt + l15) * 64 + 32 * K + 8 * quad];
                            c = MFMA16(aQ[K], bw, c);
                        }
                        #pragma unroll
                        for (int r = 0; r < 4; ++r)
                            sE[SWZ(pi * 32 + 16 * msub + 4 * quad + r, 16 * nt + l15)] = (f16)c[r];
                    }
                }
            }
            soft_barrier();
            #pragma unroll
            for (int pi = 0; pi < 3; ++pi) {
                if (pi < pcnt) {
                    #pragma unroll
                    for (int K = 0; K < 2; ++K)
                        aW[pb0 + pi][K] =
                            *(const f16x8*)&sE[SWZ(pi * 32 + 16 * msub + l15, 32 * K + 8 * quad)];
                }
            }
            soft_barrier();
        }
    }

    float ab[5];
    #pragma unroll
    for (int p = 0; p < 5; ++p) ab[p] = abs_bias[p * NH + h];

    float pf_st[5][2][4], pf_mask[2];
    f16x8 kreg[2], vreg[2], ereg[3];     // single-buffer staging registers

    const int krow = t >> 3, kcol = (t & 7) * 8;   // shared staging mapping

    auto issue_k = [&](int r0s) {
        const f16* ks = kf + ((size_t)bh * NL + r0s) * DH;
        kreg[0] = *(const f16x8*)&ks[krow * 64 + kcol];
        kreg[1] = *(const f16x8*)&ks[(krow + 32) * 64 + kcol];
    };
    auto write_k = [&]() {
        *(f16x8*)&sK[SWZ(krow, kcol)]      = kreg[0];
        *(f16x8*)&sK[SWZ(krow + 32, kcol)] = kreg[1];
    };
    auto issue_v = [&](int r0s) {
        const f16* vs = vt + (size_t)bh * DH * NL + r0s;
        vreg[0] = *(const f16x8*)&vs[(size_t)krow * NL + kcol];
        vreg[1] = *(const f16x8*)&vs[(size_t)(krow + 32) * NL + kcol];
    };
    auto write_v = [&]() {
        *(f16x8*)&sVt[SWZ(krow, kcol)]      = vreg[0];
        *(f16x8*)&sVt[SWZ(krow + 32, kcol)] = vreg[1];
    };
    auto issue_E = [&](int r0s) {
        const int ebase = l0 - r0s + 960;
        #pragma unroll
        for (int p2 = 0; p2 < 3; ++p2) {
            const int idx = t + 256 * p2;
            const int er = idx >> 3, colE = (idx & 7) * 8;
            if (er < 95)
                ereg[p2] = *(const f16x8*)&de16[(size_t)(ebase + er) * DH + colE];
        }
    };
    auto write_E = [&]() {
        #pragma unroll
        for (int p2 = 0; p2 < 3; ++p2) {
            const int idx = t + 256 * p2;
            const int er = idx >> 3, colE = (idx & 7) * 8;
            if (er < 95)
                *(f16x8*)&sE[SWZ(er, colE)] = ereg[p2];
        }
    };
    auto prefetch = [&](int r0s) {
        #pragma unroll
        for (int n = 0; n < 2; ++n) {
            const int j = 32 * npair + 16 * n + l15;
            pf_mask[n] = mask[bb * NL + r0s + j];
            #pragma unroll
            for (int r = 0; r < 4; ++r) {
                const int i = 16 * msub + 4 * quad + r;
                #pragma unroll
                for (int p = 0; p < 5; ++p)
                    pf_st[p][n][r] =
                        struct_m[((size_t)(p * NB + bb) * NL + l0 + i) * NL + r0s + j];
            }
        }
    };

    // prologue: stage K(0)/E(0) directly; V(0) stays in vreg (written in C(0))
    issue_k(0);
    issue_E(0);
    issue_v(0);
    prefetch(0);
    write_k();
    write_E();

    const int sm_i = t >> 3;
    const int sm_jb = t & 7;
    float m_cur = -INFINITY, l_cur = 0.f;
    f32x4 O[2];
    O[0] = (f32x4){0.f, 0.f, 0.f, 0.f};
    O[1] = (f32x4){0.f, 0.f, 0.f, 0.f};

    soft_barrier();                        // kt=0 staging visible

    for (int kt = 0; kt < 16; ++kt) {

        // ---- Phase B: positional band GEMMs (slim per-wave assignment) ----
        {
            // KE: jt = w, nt = 3-w+c (c = 0..2)
            f16x8 ak0 = *(f16x8*)&sK[SWZ(16 * w + l15, quad * 8)];
            f16x8 ak1 = *(f16x8*)&sK[SWZ(16 * w + l15, 32 + quad * 8)];
            #pragma unroll
            for (int c = 0; c < 3; ++c) {
                const int nt = 3 - w + c;
                f16x8 e0 = *(f16x8*)&sE[SWZ(16 * nt + l15, quad * 8)];
                f16x8 e1 = *(f16x8*)&sE[SWZ(16 * nt + l15, 32 + quad * 8)];
                f32x4 ck = (f32x4){0.f, 0.f, 0.f, 0.f};
                ck = MFMA16(ak0, e0, ck);
                ck = MFMA16(ak1, e1, ck);
                const int base = (16 * nt + l15) * 34 + 16 * w + 4 * quad;
                f16x2 lo = {(f16)ck[0], (f16)ck[1]};
                f16x2 hi = {(f16)ck[2], (f16)ck[3]};
                *(f16x2*)&sKEl[base]     = lo;
                *(f16x2*)&sKEl[base + 2] = hi;
            }
            // QE: mi = msub, nt = qs..qs+qc-1  (A-frag = resident aQ)
            const int qs = 3 * npair + msub;
            const int qc = 3 - npair;
            #pragma unroll
            for (int c = 0; c < 3; ++c) {
                if (c < qc) {
                    const int nt = qs + c;
                    f16x8 e0 = *(f16x8*)&sE[SWZ(16 * nt + l15, quad * 8)];
                    f16x8 e1 = *(f16x8*)&sE[SWZ(16 * nt + l15, 32 + quad * 8)];
                    f32x4 cq = (f32x4){0.f, 0.f, 0.f, 0.f};
                    cq = MFMA16(aQ[0], e0, cq);
                    cq = MFMA16(aQ[1], e1, cq);
                    const int base = (16 * nt + l15) * 34 + 16 * msub + 4 * quad;
                    f16x2 lo = {(f16)cq[0], (f16)cq[1]};
                    f16x2 hi = {(f16)cq[2], (f16)cq[3]};
                    *(f16x2*)&sQEl[base]     = lo;
                    *(f16x2*)&sQEl[base + 2] = hi;
                }
            }
        }
        soft_barrier();                    // bar_a: sQEl/sKEl published

        // ---- Phase C: write V(kt); issue K/V/E(kt+1); score MFMAs ----
        {
            write_v();                     // ds_write reads vreg (WAR-safe before reissue)
            if (kt < 15) {
                issue_k((kt + 1) * 64);
                issue_v((kt + 1) * 64);
                issue_E((kt + 1) * 64);
            }

            f32x4 acc[2][6];
            #pragma unroll
            for (int n = 0; n < 2; ++n)
                #pragma unroll
                for (int p = 0; p < 6; ++p)
                    acc[n][p] = (f32x4){0.f, 0.f, 0.f, 0.f};

            #pragma unroll
            for (int K = 0; K < 2; ++K) {
                const int koff = K * 32 + quad * 8;
                f16x8 bk2[2];
                #pragma unroll
                for (int n = 0; n < 2; ++n)
                    bk2[n] = *(f16x8*)&sK[SWZ(32 * npair + 16 * n + l15, koff)];
                #pragma unroll
                for (int n = 0; n < 2; ++n)
                    acc[n][0] = MFMA16(aQ[K], bk2[n], acc[n][0]);
                #pragma unroll
                for (int p = 0; p < 5; ++p)
                    #pragma unroll
                    for (int n = 0; n < 2; ++n)
                        acc[n][1 + p] = MFMA16(aW[p][K], bk2[n], acc[n][1 + p]);
            }

            #pragma unroll
            for (int n = 0; n < 2; ++n) {
                const int j = 32 * npair + 16 * n + l15;
                #pragma unroll
                for (int r = 0; r < 4; ++r) {
                    const int i = 16 * msub + 4 * quad + r;
                    const int tp = i - j + 63;
                    float posv = (float)sQEl[tp * 34 + i] + (float)sKEl[tp * 34 + j];
                    float s = (acc[n][0][r] + posv) * 0.125f + pf_mask[n];
                    #pragma unroll
                    for (int p = 0; p < 5; ++p)
                        s += (acc[n][1 + p][r] + ab[p]) * pf_st[p][n][r];
                    sS[i * 66 + j] = s;
                }
            }
        }
        soft_barrier();                    // bar_b: sS published

        // ---- Phase D: softmax; write K/E(kt+1); issue pf(kt+1) ----
        {
            float sv[8];
            float smax = -INFINITY;
            #pragma unroll
            for (int k = 0; k < 8; ++k) {
                sv[k] = sS[sm_i * 66 + sm_jb + 8 * k];
                smax = fmaxf(smax, sv[k]);
            }
            #pragma unroll
            for (int off = 4; off > 0; off >>= 1)
                smax = fmaxf(smax, __shfl_xor(smax, off, 8));
            const float m_new = fmaxf(m_cur, smax);
            const float alpha = __expf(m_cur - m_new);
            float rsum = 0.f;
            #pragma unroll
            for (int k = 0; k < 8; ++k) {
                float p = __expf(sv[k] - m_new);
                sP[SWZ(sm_i, sm_jb + 8 * k)] = (f16)p;
                rsum += p;
            }
            #pragma unroll
            for (int off = 4; off > 0; off >>= 1)
                rsum += __shfl_xor(rsum, off, 8);
            l_cur = l_cur * alpha + rsum;
            m_cur = m_new;
            if (sm_jb == 0) {
                sS[sm_i * 66 + 64] = alpha;
                sS[sm_i * 66 + 65] = l_cur;
            }

            if (kt < 15) {
                write_k();                 // vmcnt covered by C compute + softmax
                write_E();
                prefetch((kt + 1) * 64);   // reg-dest loads for next C epilogue
            }
        }
        soft_barrier();                    // bar_c: sP/alpha + staging published

        // ---- Phase E: PV MFMA only ----
        {
            float a4[4];
            #pragma unroll
            for (int r = 0; r < 4; ++r)
                a4[r] = sS[(16 * msub + 4 * quad + r) * 66 + 64];
            #pragma unroll
            for (int n = 0; n < 2; ++n)
                #pragma unroll
                for (int r = 0; r < 4; ++r) O[n][r] *= a4[r];

            #pragma unroll
            for (int K = 0; K < 2; ++K) {
                const int koff = K * 32 + quad * 8;
                f16x8 pfr = *(f16x8*)&sP[SWZ(16 * msub + l15, koff)];
                #pragma unroll
                for (int n = 0; n < 2; ++n) {
                    f16x8 vfr = *(f16x8*)&sVt[SWZ(32 * npair + 16 * n + l15, koff)];
                    O[n] = MFMA16(pfr, vfr, O[n]);
                }
            }
        }
    }

    float linv[4];
    #pragma unroll
    for (int r = 0; r < 4; ++r)
        linv[r] = 1.0f / sS[(16 * msub + 4 * quad + r) * 66 + 65];
    #pragma unroll
    for (int n = 0; n < 2; ++n) {
        const int dh = 32 * npair + 16 * n + l15;
        #pragma unroll
        for (int r = 0; r < 4; ++r) {
            const int i = 16 * msub + 4 * quad + r;
            out[((size_t)bb * NL + l0 + i) * ND + h * DH + dh] = O[n][r] * linv[r];
        }
    }
}

// ---------------------------------------------------------------------------
extern "C" void kernel_launch(void* const* d_in, const int* in_sizes, int n_in,
                              void* d_out, int out_size, void* d_ws, size_t ws_size,
                              hipStream_t stream) {
    const float* hs   = (const float*)d_in[0];
    const float* mask = (const float*)d_in[1];
    const float* stm  = (const float*)d_in[2];
    const float* Wq   = (const float*)d_in[3];
    const float* bq   = (const float*)d_in[4];
    const float* Wk   = (const float*)d_in[5];
    const float* bk   = (const float*)d_in[6];
    const float* Wv   = (const float*)d_in[7];
    const float* bv   = (const float*)d_in[8];
    const float* de   = (const float*)d_in[9];
    const float* sw   = (const float*)d_in[10];
    const float* abb  = (const float*)d_in[11];
    float* outp = (float*)d_out;

    const size_t NQKV = (size_t)NB * NH * NL * DH;       // 1,572,864
    char* ws = (char*)d_ws;
    f16* qf   = (f16*)ws;                 ws += NQKV * 2;
    f16* kf   = (f16*)ws;                 ws += NQKV * 2;
    f16* vtb  = (f16*)ws;                 ws += NQKV * 2;
    f16* wt   = (f16*)ws;                 ws += (size_t)2304 * 768 * 2;
    f16* swt  = (f16*)ws;                 ws += (size_t)245760 * 2;
    f16* de16 = (f16*)ws;                 // 2047*64 f16 = 262 KB

    prep_kernel<<<556, 256, 0, stream>>>(Wq, Wk, Wv, sw, de, wt, swt, de16);
    qkv_kernel<<<dim3(32, 18), 256, 0, stream>>>(hs, wt, bq, bk, bv, qf, kf, vtb);
    attn_kernel<<<dim3(32, 24), 256, 0, stream>>>(qf, kf, vtb, swt,
                                                  mask, stm, de16, abb, outp);
}